// Round 1
// baseline (1028.430 us; speedup 1.0000x reference)
//
#include <hip/hip_runtime.h>
#include <hip/hip_bf16.h>
#include <math.h>

#define BB 32
#define NN 1024
#define DD 64
#define HH 128
#define KK 16
#define OD 8
#define M_TOT (BB*NN)

// ---------------------------------------------------------------------------
// Branch-free sorted insert into ascending top-16 list. Strict < so that on
// exact d2 ties the earlier-scanned (lower j) element stays first — matches
// jax.lax.top_k tie-breaking (lower index first).
// ---------------------------------------------------------------------------
static __device__ __forceinline__ void insert16(float (&bd)[16], int (&bi)[16], float d2, int j) {
  bool c[16];
#pragma unroll
  for (int k = 0; k < 16; ++k) c[k] = d2 < bd[k];
#pragma unroll
  for (int k = 15; k >= 1; --k) {
    bd[k] = c[k-1] ? bd[k-1] : (c[k] ? d2 : bd[k]);
    bi[k] = c[k-1] ? bi[k-1] : (c[k] ? j  : bi[k]);
  }
  bd[0] = c[0] ? d2 : bd[0];
  bi[0] = c[0] ? j  : bi[0];
}

// ---------------------------------------------------------------------------
// K0: mask = any(obs != 0, axis=2); also zero the integer degree buffer
// (must be re-zeroed every launch — harness does not re-poison between runs).
// ---------------------------------------------------------------------------
__global__ __launch_bounds__(256) void k_mask(const float* __restrict__ obs,
                                              float* __restrict__ maskf,
                                              int* __restrict__ degi) {
  const int r = blockIdx.x * 256 + threadIdx.x;
  const float4* row = (const float4*)(obs + (size_t)r * DD);
  bool any = false;
#pragma unroll
  for (int q = 0; q < DD / 4; ++q) {
    float4 v = row[q];
    any = any || (v.x != 0.f) || (v.y != 0.f) || (v.z != 0.f) || (v.w != 0.f);
  }
  maskf[r] = any ? 1.f : 0.f;
  degi[r] = 0;
}

// ---------------------------------------------------------------------------
// K1: exact 16-NN per row (self excluded), plus integer degree scatter.
// 2 lanes per row (512 candidates each), shuffle-merge, lane half==0 writes.
// d2 uses explicit IEEE f32 mul/add (no fma contraction) to match the
// reference's rounding, so near-tie orderings agree.
// ---------------------------------------------------------------------------
__global__ __launch_bounds__(256) void k_topk(const float* __restrict__ obs,
                                              const float* __restrict__ maskf,
                                              int* __restrict__ nbr,
                                              int* __restrict__ degi) {
  __shared__ float px[NN];
  __shared__ float py[NN];
  const int b = blockIdx.x;
  const int tile = blockIdx.y;          // 8 tiles of 128 rows
  const int t = threadIdx.x;

  for (int j = t; j < NN; j += 256) {
    const float mf = maskf[b * NN + j];
    const float* p = obs + ((size_t)(b * NN + j)) * DD;
    const float x = p[0], y = p[1];
    px[j] = (mf != 0.f) ? x : __builtin_inff();   // invalid -> inf => d2 = inf/NaN, never selected
    py[j] = (mf != 0.f) ? y : __builtin_inff();
  }
  __syncthreads();

  const int row  = tile * 128 + (t >> 1);
  const int half = t & 1;
  const float xi = px[row];
  const float yi = py[row];

  float bd[16];
  int   bi[16];
#pragma unroll
  for (int k = 0; k < 16; ++k) { bd[k] = __builtin_inff(); bi[k] = k; }

  const int j0 = half * (NN / 2);
#pragma unroll 4
  for (int j = j0; j < j0 + NN / 2; ++j) {
    const float dx = __fsub_rn(xi, px[j]);
    const float dy = __fsub_rn(yi, py[j]);
    float d2 = __fadd_rn(__fmul_rn(dx, dx), __fmul_rn(dy, dy));
    if (j == row) d2 = __builtin_inff();          // exclude self (idx[...,0] in ref)
    if (d2 < bd[15]) insert16(bd, bi, d2, j);
  }

  // exchange partner's list (snapshot first — both lanes mutate)
  float od[16]; int oi[16];
#pragma unroll
  for (int k = 0; k < 16; ++k) {
    od[k] = __shfl_xor(bd[k], 1);
    oi[k] = __shfl_xor(bi[k], 1);
  }

  if (half == 0) {
    // half0 holds j in [0,512): on ties its (lower-j) elements must stay first;
    // strict < insert of partner's (higher-j) elements preserves that.
#pragma unroll
    for (int k = 0; k < 16; ++k) insert16(bd, bi, od[k], oi[k]);

    const size_t r = (size_t)b * NN + row;
    int4* nb4 = (int4*)(nbr + r * KK);
    nb4[0] = make_int4(bi[0],  bi[1],  bi[2],  bi[3]);
    nb4[1] = make_int4(bi[4],  bi[5],  bi[6],  bi[7]);
    nb4[2] = make_int4(bi[8],  bi[9],  bi[10], bi[11]);
    nb4[3] = make_int4(bi[12], bi[13], bi[14], bi[15]);

    const float mfi = maskf[r];
    if (mfi != 0.f) {
#pragma unroll
      for (int k = 0; k < 16; ++k) atomicAdd(&degi[b * NN + bi[k]], 1);
    }
  }
}

// ---------------------------------------------------------------------------
// K2: dinv = deg>0 ? rsqrt(deg) : 0, with deg = scatter_count + 2*maskf
// ---------------------------------------------------------------------------
__global__ __launch_bounds__(256) void k_dinv(const int* __restrict__ degi,
                                              const float* __restrict__ maskf,
                                              float* __restrict__ dinv) {
  const int r = blockIdx.x * 256 + threadIdx.x;
  const float deg = (float)degi[r] + 2.f * maskf[r];
  dinv[r] = (deg > 0.f) ? (1.f / sqrtf(deg)) : 0.f;
}

// ---------------------------------------------------------------------------
// K3: Y = X @ W   (no bias; bias is applied inside the GCN combine).
// Block: 16 rows x 128 cols, W fully LDS-staged.
// ---------------------------------------------------------------------------
template <int CIN>
__global__ __launch_bounds__(256) void k_gemm(const float* __restrict__ X,
                                              const float* __restrict__ W,
                                              float* __restrict__ Y) {
  __shared__ float Ws[CIN * HH];
  __shared__ float Xs[16 * CIN];
  const int t = threadIdx.x;
  const size_t rowbase = (size_t)blockIdx.x * 16;

  const float4* W4 = (const float4*)W;
  for (int q = t; q < CIN * HH / 4; q += 256) ((float4*)Ws)[q] = W4[q];
  const float4* X4 = (const float4*)(X + rowbase * CIN);
  for (int q = t; q < 16 * CIN / 4; q += 256) ((float4*)Xs)[q] = X4[q];
  __syncthreads();

  const int c4 = (t & 31) * 4;
  const int r0 = (t >> 5) * 2;

  float a0x = 0.f, a0y = 0.f, a0z = 0.f, a0w = 0.f;
  float a1x = 0.f, a1y = 0.f, a1z = 0.f, a1w = 0.f;
#pragma unroll 8
  for (int k = 0; k < CIN; ++k) {
    const float xa = Xs[r0 * CIN + k];
    const float xb = Xs[(r0 + 1) * CIN + k];
    const float4 w = *(const float4*)&Ws[k * HH + c4];
    a0x += xa * w.x; a0y += xa * w.y; a0z += xa * w.z; a0w += xa * w.w;
    a1x += xb * w.x; a1y += xb * w.y; a1z += xb * w.z; a1w += xb * w.w;
  }
  float4* y0 = (float4*)(Y + (rowbase + r0) * HH + c4);
  float4* y1 = (float4*)(Y + (rowbase + r0 + 1) * HH + c4);
  *y0 = make_float4(a0x, a0y, a0z, a0w);
  *y1 = make_float4(a1x, a1y, a1z, a1w);
}

// ---------------------------------------------------------------------------
// K4: GCN scatter + combine for one (batch, 16-channel chunk).
// agg lives in LDS [1024][17] (pad 17 -> random bank spread for ds_add_f32).
// h = tanh(dinv*agg + 2*dinv^2*y + bias)
// ---------------------------------------------------------------------------
__global__ __launch_bounds__(1024) void k_gcn(const float* __restrict__ y,
                                              const float* __restrict__ dinv,
                                              const float* __restrict__ maskf,
                                              const int* __restrict__ nbr,
                                              const float* __restrict__ bias,
                                              float* __restrict__ hout) {
  __shared__ float agg[NN * 17];
  const int b = blockIdx.x;
  const int c0 = blockIdx.y * 16;
  const int i = threadIdx.x;

  for (int q = i; q < NN * 17; q += 1024) agg[q] = 0.f;
  __syncthreads();

  const size_t r = (size_t)b * NN + i;
  const float di = dinv[r];
  const float s  = di * maskf[r];

  float yv[16];
  {
    const float4* yrow = (const float4*)(y + r * HH + c0);
#pragma unroll
    for (int q = 0; q < 4; ++q) {
      float4 v = yrow[q];
      yv[q * 4 + 0] = v.x; yv[q * 4 + 1] = v.y;
      yv[q * 4 + 2] = v.z; yv[q * 4 + 3] = v.w;
    }
  }
  int nb[16];
  {
    const int4* nrow = (const int4*)(nbr + r * KK);
#pragma unroll
    for (int q = 0; q < 4; ++q) {
      int4 v = nrow[q];
      nb[q * 4 + 0] = v.x; nb[q * 4 + 1] = v.y;
      nb[q * 4 + 2] = v.z; nb[q * 4 + 3] = v.w;
    }
  }
  float u[16];
#pragma unroll
  for (int c = 0; c < 16; ++c) u[c] = s * yv[c];

#pragma unroll
  for (int k = 0; k < 16; ++k) {
    float* dst = &agg[nb[k] * 17];
#pragma unroll
    for (int c = 0; c < 16; ++c) atomicAdd(&dst[c], u[c]);
  }
  __syncthreads();

  const float t2 = 2.f * di * di;
  float hv[16];
#pragma unroll
  for (int c = 0; c < 16; ++c) {
    const float o = di * agg[i * 17 + c] + t2 * yv[c] + bias[c0 + c];
    hv[c] = tanhf(o);
  }
  float4* hrow = (float4*)(hout + r * HH + c0);
#pragma unroll
  for (int q = 0; q < 4; ++q)
    hrow[q] = make_float4(hv[q * 4 + 0], hv[q * 4 + 1], hv[q * 4 + 2], hv[q * 4 + 3]);
}

// ---------------------------------------------------------------------------
// K5: out = (h @ W_out + b_out) * maskf
// ---------------------------------------------------------------------------
__global__ __launch_bounds__(256) void k_out(const float* __restrict__ h,
                                             const float* __restrict__ Wo,
                                             const float* __restrict__ bo,
                                             const float* __restrict__ maskf,
                                             float* __restrict__ out) {
  __shared__ float Ws[HH * OD];
  __shared__ float bs[OD];
  const int t = threadIdx.x;
  for (int q = t; q < HH * OD / 4; q += 256) ((float4*)Ws)[q] = ((const float4*)Wo)[q];
  if (t < OD) bs[t] = bo[t];
  __syncthreads();

  const size_t r = (size_t)blockIdx.x * 256 + t;
  const float4* hrow = (const float4*)(h + r * HH);
  float acc[OD];
#pragma unroll
  for (int o = 0; o < OD; ++o) acc[o] = 0.f;

#pragma unroll 4
  for (int q = 0; q < HH / 4; ++q) {
    const float4 hv = hrow[q];
    const float* w = &Ws[(q * 4) * OD];
#pragma unroll
    for (int o = 0; o < OD; ++o) acc[o] += hv.x * w[o];
#pragma unroll
    for (int o = 0; o < OD; ++o) acc[o] += hv.y * w[OD + o];
#pragma unroll
    for (int o = 0; o < OD; ++o) acc[o] += hv.z * w[2 * OD + o];
#pragma unroll
    for (int o = 0; o < OD; ++o) acc[o] += hv.w * w[3 * OD + o];
  }
  const float mf = maskf[r];
  float4* orow = (float4*)(out + r * OD);
  orow[0] = make_float4((acc[0] + bs[0]) * mf, (acc[1] + bs[1]) * mf,
                        (acc[2] + bs[2]) * mf, (acc[3] + bs[3]) * mf);
  orow[1] = make_float4((acc[4] + bs[4]) * mf, (acc[5] + bs[5]) * mf,
                        (acc[6] + bs[6]) * mf, (acc[7] + bs[7]) * mf);
}

// ---------------------------------------------------------------------------
extern "C" void kernel_launch(void* const* d_in, const int* in_sizes, int n_in,
                              void* d_out, int out_size, void* d_ws, size_t ws_size,
                              hipStream_t stream) {
  (void)in_sizes; (void)n_in; (void)out_size; (void)ws_size;
  const float* obs = (const float*)d_in[0];
  const float* W1  = (const float*)d_in[1];
  const float* b1  = (const float*)d_in[2];
  const float* W2  = (const float*)d_in[3];
  const float* b2  = (const float*)d_in[4];
  const float* Wo  = (const float*)d_in[5];
  const float* bo  = (const float*)d_in[6];
  float* out = (float*)d_out;

  char* ws = (char*)d_ws;
  float* maskf = (float*)(ws);                                   // 128 KB
  int*   degi  = (int*)  (ws + (size_t)(128 << 10));             // 128 KB
  float* dinv  = (float*)(ws + (size_t)(256 << 10));             // 128 KB
  int*   nbr   = (int*)  (ws + (size_t)(384 << 10));             // 2 MB
  float* ybuf  = (float*)(ws + (size_t)(384 << 10) + (2u << 20));            // 16 MB
  float* hbuf  = (float*)(ws + (size_t)(384 << 10) + (2u << 20) + (16u << 20)); // 16 MB

  k_mask<<<M_TOT / 256, 256, 0, stream>>>(obs, maskf, degi);
  k_topk<<<dim3(BB, 8), 256, 0, stream>>>(obs, maskf, nbr, degi);
  k_dinv<<<M_TOT / 256, 256, 0, stream>>>(degi, maskf, dinv);

  k_gemm<DD><<<M_TOT / 16, 256, 0, stream>>>(obs, W1, ybuf);
  k_gcn<<<dim3(BB, HH / 16), 1024, 0, stream>>>(ybuf, dinv, maskf, nbr, b1, hbuf);
  k_gemm<HH><<<M_TOT / 16, 256, 0, stream>>>(hbuf, W2, ybuf);
  k_gcn<<<dim3(BB, HH / 16), 1024, 0, stream>>>(ybuf, dinv, maskf, nbr, b2, hbuf);
  k_out<<<M_TOT / 256, 256, 0, stream>>>(hbuf, Wo, bo, maskf, out);
}

// Round 2
// 407.941 us; speedup vs baseline: 2.5210x; 2.5210x over previous
//
#include <hip/hip_runtime.h>
#include <hip/hip_bf16.h>
#include <math.h>

#define BB 32
#define NN 1024
#define DD 64
#define HH 128
#define KK 16
#define OD 8
#define M_TOT (BB*NN)

// ---------------------------------------------------------------------------
// Branch-free sorted insert into ascending top-16 list. Strict < so that on
// exact d2 ties the earlier-scanned (lower j) element stays first — matches
// jax.lax.top_k tie-breaking (lower index first).
// ---------------------------------------------------------------------------
static __device__ __forceinline__ void insert16(float (&bd)[16], int (&bi)[16], float d2, int j) {
  bool c[16];
#pragma unroll
  for (int k = 0; k < 16; ++k) c[k] = d2 < bd[k];
#pragma unroll
  for (int k = 15; k >= 1; --k) {
    bd[k] = c[k-1] ? bd[k-1] : (c[k] ? d2 : bd[k]);
    bi[k] = c[k-1] ? bi[k-1] : (c[k] ? j  : bi[k]);
  }
  bd[0] = c[0] ? d2 : bd[0];
  bi[0] = c[0] ? j  : bi[0];
}

// ---------------------------------------------------------------------------
// K0: mask = any(obs != 0, axis=2); zero integer degree buffer (must be
// re-zeroed every launch — harness does not re-poison between replays).
// ---------------------------------------------------------------------------
__global__ __launch_bounds__(256) void k_mask(const float* __restrict__ obs,
                                              float* __restrict__ maskf,
                                              int* __restrict__ degi) {
  const int r = blockIdx.x * 256 + threadIdx.x;
  const float4* row = (const float4*)(obs + (size_t)r * DD);
  bool any = false;
#pragma unroll
  for (int q = 0; q < DD / 4; ++q) {
    float4 v = row[q];
    any = any || (v.x != 0.f) || (v.y != 0.f) || (v.z != 0.f) || (v.w != 0.f);
  }
  maskf[r] = any ? 1.f : 0.f;
  degi[r] = 0;
}

// ---------------------------------------------------------------------------
// K1: exact 16-NN per row (self excluded) + integer in-degree scatter.
// 2 lanes per row (512 candidates each), shuffle-merge, lane half==0 writes.
// Explicit IEEE f32 ops (no fma contraction) so near-tie orderings match ref.
// ---------------------------------------------------------------------------
__global__ __launch_bounds__(256) void k_topk(const float* __restrict__ obs,
                                              const float* __restrict__ maskf,
                                              int* __restrict__ nbr,
                                              int* __restrict__ degi) {
  __shared__ float px[NN];
  __shared__ float py[NN];
  const int b = blockIdx.x;
  const int tile = blockIdx.y;          // 8 tiles of 128 rows
  const int t = threadIdx.x;

  for (int j = t; j < NN; j += 256) {
    const float mf = maskf[b * NN + j];
    const float* p = obs + ((size_t)(b * NN + j)) * DD;
    const float x = p[0], y = p[1];
    px[j] = (mf != 0.f) ? x : __builtin_inff();   // invalid -> never selected
    py[j] = (mf != 0.f) ? y : __builtin_inff();
  }
  __syncthreads();

  const int row  = tile * 128 + (t >> 1);
  const int half = t & 1;
  const float xi = px[row];
  const float yi = py[row];

  float bd[16];
  int   bi[16];
#pragma unroll
  for (int k = 0; k < 16; ++k) { bd[k] = __builtin_inff(); bi[k] = k; }

  const int j0 = half * (NN / 2);
#pragma unroll 4
  for (int j = j0; j < j0 + NN / 2; ++j) {
    const float dx = __fsub_rn(xi, px[j]);
    const float dy = __fsub_rn(yi, py[j]);
    float d2 = __fadd_rn(__fmul_rn(dx, dx), __fmul_rn(dy, dy));
    if (j == row) d2 = __builtin_inff();          // exclude self
    if (d2 < bd[15]) insert16(bd, bi, d2, j);
  }

  float od[16]; int oi[16];
#pragma unroll
  for (int k = 0; k < 16; ++k) {
    od[k] = __shfl_xor(bd[k], 1);
    oi[k] = __shfl_xor(bi[k], 1);
  }

  if (half == 0) {
#pragma unroll
    for (int k = 0; k < 16; ++k) insert16(bd, bi, od[k], oi[k]);

    const size_t r = (size_t)b * NN + row;
    int4* nb4 = (int4*)(nbr + r * KK);
    nb4[0] = make_int4(bi[0],  bi[1],  bi[2],  bi[3]);
    nb4[1] = make_int4(bi[4],  bi[5],  bi[6],  bi[7]);
    nb4[2] = make_int4(bi[8],  bi[9],  bi[10], bi[11]);
    nb4[3] = make_int4(bi[12], bi[13], bi[14], bi[15]);

    if (maskf[r] != 0.f) {
#pragma unroll
      for (int k = 0; k < 16; ++k) atomicAdd(&degi[b * NN + bi[k]], 1);
    }
  }
}

// ---------------------------------------------------------------------------
// K2: dinv = deg>0 ? rsqrt(deg) : 0 (deg = in_count + 2*maskf); s = dinv*maskf
// ---------------------------------------------------------------------------
__global__ __launch_bounds__(256) void k_dinv(const int* __restrict__ degi,
                                              const float* __restrict__ maskf,
                                              float* __restrict__ dinv,
                                              float* __restrict__ sbuf) {
  const int r = blockIdx.x * 256 + threadIdx.x;
  const float m = maskf[r];
  const float deg = (float)degi[r] + 2.f * m;
  const float dv = (deg > 0.f) ? (1.f / sqrtf(deg)) : 0.f;
  dinv[r] = dv;
  sbuf[r] = dv * m;
}

// ---------------------------------------------------------------------------
// K3: per-batch exclusive prefix sum of in-degrees -> CSR cursor base.
// cur[r] = b*16384 + exclusive_scan(degi within batch)
// ---------------------------------------------------------------------------
__global__ __launch_bounds__(1024) void k_scan(const int* __restrict__ degi,
                                               int* __restrict__ cur) {
  __shared__ int wsum[16];
  const int b = blockIdx.x, t = threadIdx.x;
  const int lane = t & 63, w = t >> 6;
  const int d = degi[b * NN + t];
  int x = d;
#pragma unroll
  for (int off = 1; off < 64; off <<= 1) {
    int y = __shfl_up(x, off, 64);
    if (lane >= off) x += y;
  }
  if (lane == 63) wsum[w] = x;
  __syncthreads();
  if (w == 0) {
    int v = (lane < 16) ? wsum[lane] : 0;
#pragma unroll
    for (int off = 1; off < 16; off <<= 1) {
      int y = __shfl_up(v, off, 64);
      if (lane >= off) v += y;
    }
    if (lane < 16) wsum[lane] = v;
  }
  __syncthreads();
  const int base = b * (NN * KK) + (w ? wsum[w - 1] : 0);
  cur[b * NN + t] = base + x - d;   // exclusive
}

// ---------------------------------------------------------------------------
// K4: fill reverse edge list. rev[pos] = (src_flat, bitcast(s_src)).
// After this, cur[r] = start(r) + cnt(r), so start = cur[r] - degi[r].
// ---------------------------------------------------------------------------
__global__ __launch_bounds__(256) void k_fill(const int* __restrict__ nbr,
                                              const float* __restrict__ maskf,
                                              const float* __restrict__ sbuf,
                                              int* __restrict__ cur,
                                              int2* __restrict__ rev) {
  const int r = blockIdx.x * 256 + threadIdx.x;
  if (maskf[r] == 0.f) return;
  const int bbase = r & ~(NN - 1);
  const float sv = sbuf[r];
  const int4* n4 = (const int4*)(nbr + (size_t)r * KK);
#pragma unroll
  for (int q = 0; q < 4; ++q) {
    int4 v = n4[q];
    int nb[4] = {v.x, v.y, v.z, v.w};
#pragma unroll
    for (int u = 0; u < 4; ++u) {
      const int pos = atomicAdd(&cur[bbase + nb[u]], 1);
      rev[pos] = make_int2(r, __float_as_int(sv));
    }
  }
}

// ---------------------------------------------------------------------------
// K5: Y = X @ W. 64 rows x 128 cols per block, 512 threads, 4x4 acc/thread.
// K-tiled (32): W tile straight copy, X tile transposed into LDS (pad 68
// keeps float4 alignment + spreads banks). Inner loop: 2x b128 (one
// broadcast) per 16 FMA -> compute-bound.
// ---------------------------------------------------------------------------
template <int CIN>
__global__ __launch_bounds__(512) void k_gemm(const float* __restrict__ X,
                                              const float* __restrict__ W,
                                              float* __restrict__ Y) {
  __shared__ float Ws[32 * HH];      // 16 KB
  __shared__ float Xt[32 * 68];      // 8.5 KB, Xt[k][row]
  const int t = threadIdx.x;
  const size_t rowbase = (size_t)blockIdx.x * 64;

  const int c4 = (t & 31) * 4;
  const int r4 = (t >> 5) * 4;

  float acc[4][4] = {{0.f}};

  for (int k0 = 0; k0 < CIN; k0 += 32) {
    __syncthreads();
    {
      const float4* Wt4 = (const float4*)(W + (size_t)k0 * HH);
      ((float4*)Ws)[t]       = Wt4[t];
      ((float4*)Ws)[t + 512] = Wt4[t + 512];
    }
    {
      const int row = t >> 3;        // 0..63
      const int kq  = t & 7;         // 0..7
      float4 v = *(const float4*)(X + (rowbase + row) * CIN + k0 + kq * 4);
      Xt[(kq * 4 + 0) * 68 + row] = v.x;
      Xt[(kq * 4 + 1) * 68 + row] = v.y;
      Xt[(kq * 4 + 2) * 68 + row] = v.z;
      Xt[(kq * 4 + 3) * 68 + row] = v.w;
    }
    __syncthreads();
#pragma unroll
    for (int k = 0; k < 32; ++k) {
      const float4 xa = *(const float4*)&Xt[k * 68 + r4];
      const float4 wb = *(const float4*)&Ws[k * HH + c4];
      acc[0][0] += xa.x * wb.x; acc[0][1] += xa.x * wb.y; acc[0][2] += xa.x * wb.z; acc[0][3] += xa.x * wb.w;
      acc[1][0] += xa.y * wb.x; acc[1][1] += xa.y * wb.y; acc[1][2] += xa.y * wb.z; acc[1][3] += xa.y * wb.w;
      acc[2][0] += xa.z * wb.x; acc[2][1] += xa.z * wb.y; acc[2][2] += xa.z * wb.z; acc[2][3] += xa.z * wb.w;
      acc[3][0] += xa.w * wb.x; acc[3][1] += xa.w * wb.y; acc[3][2] += xa.w * wb.z; acc[3][3] += xa.w * wb.w;
    }
  }
#pragma unroll
  for (int i = 0; i < 4; ++i)
    *(float4*)(Y + (rowbase + r4 + i) * HH + c4) =
        make_float4(acc[i][0], acc[i][1], acc[i][2], acc[i][3]);
}

// ---------------------------------------------------------------------------
// K6: GCN via reverse-CSR gather. 32 lanes per node, each owns 4 channels.
// h = tanh(dinv*agg + 2*dinv^2*y + bias), agg = sum_e s_e * y[src_e].
// ---------------------------------------------------------------------------
__global__ __launch_bounds__(256) void k_gcn(const float* __restrict__ y,
                                             const float* __restrict__ dinv,
                                             const int* __restrict__ degi,
                                             const int* __restrict__ cur,
                                             const int2* __restrict__ rev,
                                             const float* __restrict__ bias,
                                             float* __restrict__ hout) {
  const int t = threadIdx.x;
  const int r = blockIdx.x * 8 + (t >> 5);
  const int lane = t & 31;
  const int cnt = degi[r];
  const int off = cur[r] - cnt;      // cur was bumped by exactly cnt in k_fill
  const float di = dinv[r];

  float4 acc = make_float4(0.f, 0.f, 0.f, 0.f);
  int e = 0;
  for (; e + 2 <= cnt; e += 2) {
    const int2 e0 = rev[off + e];
    const int2 e1 = rev[off + e + 1];
    const float4 y0 = *(const float4*)(y + (size_t)e0.x * HH + lane * 4);
    const float4 y1 = *(const float4*)(y + (size_t)e1.x * HH + lane * 4);
    const float s0 = __int_as_float(e0.y);
    const float s1 = __int_as_float(e1.y);
    acc.x += s0 * y0.x; acc.y += s0 * y0.y; acc.z += s0 * y0.z; acc.w += s0 * y0.w;
    acc.x += s1 * y1.x; acc.y += s1 * y1.y; acc.z += s1 * y1.z; acc.w += s1 * y1.w;
  }
  if (e < cnt) {
    const int2 e0 = rev[off + e];
    const float4 y0 = *(const float4*)(y + (size_t)e0.x * HH + lane * 4);
    const float s0 = __int_as_float(e0.y);
    acc.x += s0 * y0.x; acc.y += s0 * y0.y; acc.z += s0 * y0.z; acc.w += s0 * y0.w;
  }

  const float4 ys = *(const float4*)(y + (size_t)r * HH + lane * 4);
  const float4 bb = *(const float4*)(bias + lane * 4);
  const float t2 = 2.f * di * di;
  float4 h;
  h.x = tanhf(di * acc.x + t2 * ys.x + bb.x);
  h.y = tanhf(di * acc.y + t2 * ys.y + bb.y);
  h.z = tanhf(di * acc.z + t2 * ys.z + bb.z);
  h.w = tanhf(di * acc.w + t2 * ys.w + bb.w);
  *(float4*)(hout + (size_t)r * HH + lane * 4) = h;
}

// ---------------------------------------------------------------------------
// K7: out = (h @ W_out + b_out) * maskf
// ---------------------------------------------------------------------------
__global__ __launch_bounds__(256) void k_out(const float* __restrict__ h,
                                             const float* __restrict__ Wo,
                                             const float* __restrict__ bo,
                                             const float* __restrict__ maskf,
                                             float* __restrict__ out) {
  __shared__ float Ws[HH * OD];
  __shared__ float bs[OD];
  const int t = threadIdx.x;
  for (int q = t; q < HH * OD / 4; q += 256) ((float4*)Ws)[q] = ((const float4*)Wo)[q];
  if (t < OD) bs[t] = bo[t];
  __syncthreads();

  const size_t r = (size_t)blockIdx.x * 256 + t;
  const float4* hrow = (const float4*)(h + r * HH);
  float acc[OD];
#pragma unroll
  for (int o = 0; o < OD; ++o) acc[o] = 0.f;

#pragma unroll 4
  for (int q = 0; q < HH / 4; ++q) {
    const float4 hv = hrow[q];
    const float* w = &Ws[(q * 4) * OD];
#pragma unroll
    for (int o = 0; o < OD; ++o) acc[o] += hv.x * w[o];
#pragma unroll
    for (int o = 0; o < OD; ++o) acc[o] += hv.y * w[OD + o];
#pragma unroll
    for (int o = 0; o < OD; ++o) acc[o] += hv.z * w[2 * OD + o];
#pragma unroll
    for (int o = 0; o < OD; ++o) acc[o] += hv.w * w[3 * OD + o];
  }
  const float mf = maskf[r];
  float4* orow = (float4*)(out + r * OD);
  orow[0] = make_float4((acc[0] + bs[0]) * mf, (acc[1] + bs[1]) * mf,
                        (acc[2] + bs[2]) * mf, (acc[3] + bs[3]) * mf);
  orow[1] = make_float4((acc[4] + bs[4]) * mf, (acc[5] + bs[5]) * mf,
                        (acc[6] + bs[6]) * mf, (acc[7] + bs[7]) * mf);
}

// ---------------------------------------------------------------------------
extern "C" void kernel_launch(void* const* d_in, const int* in_sizes, int n_in,
                              void* d_out, int out_size, void* d_ws, size_t ws_size,
                              hipStream_t stream) {
  (void)in_sizes; (void)n_in; (void)out_size; (void)ws_size;
  const float* obs = (const float*)d_in[0];
  const float* W1  = (const float*)d_in[1];
  const float* b1  = (const float*)d_in[2];
  const float* W2  = (const float*)d_in[3];
  const float* b2  = (const float*)d_in[4];
  const float* Wo  = (const float*)d_in[5];
  const float* bo  = (const float*)d_in[6];
  float* out = (float*)d_out;

  char* ws = (char*)d_ws;
  float* maskf = (float*)(ws);                             // 128 KB
  int*   degi  = (int*)  (ws + (size_t)(128 << 10));       // 128 KB
  float* dinv  = (float*)(ws + (size_t)(256 << 10));       // 128 KB
  float* sbuf  = (float*)(ws + (size_t)(384 << 10));       // 128 KB
  int*   cur   = (int*)  (ws + (size_t)(512 << 10));       // 128 KB
  int*   nbr   = (int*)  (ws + (size_t)(1u << 20));        // 2 MB
  int2*  rev   = (int2*) (ws + (size_t)(3u << 20));        // 4 MB
  float* ybuf  = (float*)(ws + (size_t)(7u << 20));        // 16 MB
  float* hbuf  = (float*)(ws + (size_t)(23u << 20));       // 16 MB

  k_mask<<<M_TOT / 256, 256, 0, stream>>>(obs, maskf, degi);
  k_topk<<<dim3(BB, 8), 256, 0, stream>>>(obs, maskf, nbr, degi);
  k_dinv<<<M_TOT / 256, 256, 0, stream>>>(degi, maskf, dinv, sbuf);
  k_scan<<<BB, 1024, 0, stream>>>(degi, cur);
  k_fill<<<M_TOT / 256, 256, 0, stream>>>(nbr, maskf, sbuf, cur, rev);

  k_gemm<DD><<<M_TOT / 64, 512, 0, stream>>>(obs, W1, ybuf);
  k_gcn<<<M_TOT / 8, 256, 0, stream>>>(ybuf, dinv, degi, cur, rev, b1, hbuf);
  k_gemm<HH><<<M_TOT / 64, 512, 0, stream>>>(hbuf, W2, ybuf);
  k_gcn<<<M_TOT / 8, 256, 0, stream>>>(ybuf, dinv, degi, cur, rev, b2, hbuf);
  k_out<<<M_TOT / 256, 256, 0, stream>>>(hbuf, Wo, bo, maskf, out);
}

// Round 3
// 230.653 us; speedup vs baseline: 4.4588x; 1.7686x over previous
//
#include <hip/hip_runtime.h>
#include <hip/hip_bf16.h>
#include <math.h>

#define BB 32
#define NN 1024
#define DD 64
#define HH 128
#define KK 16
#define OD 8
#define M_TOT (BB*NN)

typedef unsigned long long u64;

// ---------------------------------------------------------------------------
// Sorted insert into ascending top-16 of packed keys (d2_bits<<10 | idx).
// Keys are globally distinct -> exact reference semantics (lowest idx on tie).
// ---------------------------------------------------------------------------
static __device__ __forceinline__ void insert16u(u64 (&bd)[16], u64 key) {
  bool c[16];
#pragma unroll
  for (int k = 0; k < 16; ++k) c[k] = key < bd[k];
#pragma unroll
  for (int k = 15; k >= 1; --k)
    bd[k] = c[k-1] ? bd[k-1] : (c[k] ? key : bd[k]);
  bd[0] = c[0] ? key : bd[0];
}

// Bitonic merge of this lane's ascending 16-list with lane^D's ascending
// 16-list -> ascending smallest-16 of the union. Exact (keys distinct).
template <int D>
static __device__ __forceinline__ void merge16(u64 (&a)[16]) {
  u64 b[16];
#pragma unroll
  for (int i = 0; i < 16; ++i) b[i] = __shfl_xor(a[15 - i], D);
#pragma unroll
  for (int i = 0; i < 16; ++i) a[i] = (a[i] < b[i]) ? a[i] : b[i];   // bitonic seq
#pragma unroll
  for (int k = 8; k >= 1; k >>= 1) {
#pragma unroll
    for (int i = 0; i < 16; ++i) {
      if (!(i & k)) {
        const u64 x = a[i], y = a[i | k];
        a[i]     = (x < y) ? x : y;
        a[i | k] = (x < y) ? y : x;
      }
    }
  }
}

// ---------------------------------------------------------------------------
// K0: mask = any(obs != 0, axis=2); zero degree buffer; emit masked (x,y).
// ---------------------------------------------------------------------------
__global__ __launch_bounds__(256) void k_mask(const float* __restrict__ obs,
                                              float* __restrict__ maskf,
                                              int* __restrict__ degi,
                                              float2* __restrict__ pxy) {
  const int r = blockIdx.x * 256 + threadIdx.x;
  const float4* row = (const float4*)(obs + (size_t)r * DD);
  const float4 v0 = row[0];
  bool any = false;
#pragma unroll
  for (int q = 0; q < DD / 4; ++q) {
    float4 v = row[q];
    any = any || (v.x != 0.f) || (v.y != 0.f) || (v.z != 0.f) || (v.w != 0.f);
  }
  maskf[r] = any ? 1.f : 0.f;
  degi[r] = 0;
  const float inf = __builtin_inff();
  pxy[r] = any ? make_float2(v0.x, v0.y) : make_float2(inf, inf);
}

// ---------------------------------------------------------------------------
// K1: exact 16-NN per row. 8 lanes/row (lane s scans j = c*8+s), packed-key
// insert-16 per lane, 3-level bitonic shfl merge, lane s==0 writes + degrees.
// Explicit IEEE f32 ops (no fma contraction) match reference rounding.
// ---------------------------------------------------------------------------
__global__ __launch_bounds__(256) void k_topk(const float2* __restrict__ pxy,
                                              const float* __restrict__ maskf,
                                              int* __restrict__ nbr,
                                              int* __restrict__ degi) {
  __shared__ float2 pls[NN];
  const int b = blockIdx.x;
  const int t = threadIdx.x;

  for (int q = t; q < NN; q += 256) pls[q] = pxy[b * NN + q];
  __syncthreads();

  const int l = t & 63;
  const int s = l & 7;                                  // sub-lane within row group
  const int row = blockIdx.y * 32 + (t >> 6) * 8 + (l >> 3);
  const float2 pi = pls[row];
  const float xi = pi.x, yi = pi.y;
  const int cself = (s == (row & 7)) ? (row >> 3) : -1;

  u64 bd[16];
#pragma unroll
  for (int k = 0; k < 16; ++k) bd[k] = ~0ull;

  for (int c = 0; c < NN / 8; ++c) {
    const float2 p = pls[c * 8 + s];
    const float dx = __fsub_rn(xi, p.x);
    const float dy = __fsub_rn(yi, p.y);
    const float d2 = __fadd_rn(__fmul_rn(dx, dx), __fmul_rn(dy, dy));
    u64 key = ((u64)__float_as_uint(d2) << 10) | (unsigned)(c * 8 + s);
    if (c == cself) key = ~0ull;                        // exclude self
    if (key < bd[15]) insert16u(bd, key);
  }

  merge16<1>(bd);
  merge16<2>(bd);
  merge16<4>(bd);

  if (s == 0) {
    int idx[16];
#pragma unroll
    for (int k = 0; k < 16; ++k) idx[k] = (int)(bd[k] & (u64)(NN - 1));

    const size_t r = (size_t)b * NN + row;
    int4* nb4 = (int4*)(nbr + r * KK);
    nb4[0] = make_int4(idx[0],  idx[1],  idx[2],  idx[3]);
    nb4[1] = make_int4(idx[4],  idx[5],  idx[6],  idx[7]);
    nb4[2] = make_int4(idx[8],  idx[9],  idx[10], idx[11]);
    nb4[3] = make_int4(idx[12], idx[13], idx[14], idx[15]);

    if (maskf[r] != 0.f) {
#pragma unroll
      for (int k = 0; k < 16; ++k) atomicAdd(&degi[b * NN + idx[k]], 1);
    }
  }
}

// ---------------------------------------------------------------------------
// K2: dinv = deg>0 ? rsqrt(deg) : 0 (deg = in_count + 2*maskf); s = dinv*maskf
// ---------------------------------------------------------------------------
__global__ __launch_bounds__(256) void k_dinv(const int* __restrict__ degi,
                                              const float* __restrict__ maskf,
                                              float* __restrict__ dinv,
                                              float* __restrict__ sbuf) {
  const int r = blockIdx.x * 256 + threadIdx.x;
  const float m = maskf[r];
  const float deg = (float)degi[r] + 2.f * m;
  const float dv = (deg > 0.f) ? (1.f / sqrtf(deg)) : 0.f;
  dinv[r] = dv;
  sbuf[r] = dv * m;
}

// ---------------------------------------------------------------------------
// K3: per-batch exclusive prefix sum of in-degrees -> CSR cursor base.
// ---------------------------------------------------------------------------
__global__ __launch_bounds__(1024) void k_scan(const int* __restrict__ degi,
                                               int* __restrict__ cur) {
  __shared__ int wsum[16];
  const int b = blockIdx.x, t = threadIdx.x;
  const int lane = t & 63, w = t >> 6;
  const int d = degi[b * NN + t];
  int x = d;
#pragma unroll
  for (int off = 1; off < 64; off <<= 1) {
    int y = __shfl_up(x, off, 64);
    if (lane >= off) x += y;
  }
  if (lane == 63) wsum[w] = x;
  __syncthreads();
  if (w == 0) {
    int v = (lane < 16) ? wsum[lane] : 0;
#pragma unroll
    for (int off = 1; off < 16; off <<= 1) {
      int y = __shfl_up(v, off, 64);
      if (lane >= off) v += y;
    }
    if (lane < 16) wsum[lane] = v;
  }
  __syncthreads();
  const int base = b * (NN * KK) + (w ? wsum[w - 1] : 0);
  cur[b * NN + t] = base + x - d;   // exclusive
}

// ---------------------------------------------------------------------------
// K4: fill reverse edge list. rev[pos] = (src_flat, bitcast(s_src)).
// ---------------------------------------------------------------------------
__global__ __launch_bounds__(256) void k_fill(const int* __restrict__ nbr,
                                              const float* __restrict__ maskf,
                                              const float* __restrict__ sbuf,
                                              int* __restrict__ cur,
                                              int2* __restrict__ rev) {
  const int r = blockIdx.x * 256 + threadIdx.x;
  if (maskf[r] == 0.f) return;
  const int bbase = r & ~(NN - 1);
  const float sv = sbuf[r];
  const int4* n4 = (const int4*)(nbr + (size_t)r * KK);
#pragma unroll
  for (int q = 0; q < 4; ++q) {
    int4 v = n4[q];
    int nb[4] = {v.x, v.y, v.z, v.w};
#pragma unroll
    for (int u = 0; u < 4; ++u) {
      const int pos = atomicAdd(&cur[bbase + nb[u]], 1);
      rev[pos] = make_int2(r, __float_as_int(sv));
    }
  }
}

// ---------------------------------------------------------------------------
// K5: Y = X @ W. 64 rows x 128 cols per block, 512 threads, 4x4 acc/thread.
// ---------------------------------------------------------------------------
template <int CIN>
__global__ __launch_bounds__(512) void k_gemm(const float* __restrict__ X,
                                              const float* __restrict__ W,
                                              float* __restrict__ Y) {
  __shared__ float Ws[32 * HH];      // 16 KB
  __shared__ float Xt[32 * 68];      // 8.5 KB, Xt[k][row]
  const int t = threadIdx.x;
  const size_t rowbase = (size_t)blockIdx.x * 64;

  const int c4 = (t & 31) * 4;
  const int r4 = (t >> 5) * 4;

  float acc[4][4] = {{0.f}};

  for (int k0 = 0; k0 < CIN; k0 += 32) {
    __syncthreads();
    {
      const float4* Wt4 = (const float4*)(W + (size_t)k0 * HH);
      ((float4*)Ws)[t]       = Wt4[t];
      ((float4*)Ws)[t + 512] = Wt4[t + 512];
    }
    {
      const int row = t >> 3;        // 0..63
      const int kq  = t & 7;         // 0..7
      float4 v = *(const float4*)(X + (rowbase + row) * CIN + k0 + kq * 4);
      Xt[(kq * 4 + 0) * 68 + row] = v.x;
      Xt[(kq * 4 + 1) * 68 + row] = v.y;
      Xt[(kq * 4 + 2) * 68 + row] = v.z;
      Xt[(kq * 4 + 3) * 68 + row] = v.w;
    }
    __syncthreads();
#pragma unroll
    for (int k = 0; k < 32; ++k) {
      const float4 xa = *(const float4*)&Xt[k * 68 + r4];
      const float4 wb = *(const float4*)&Ws[k * HH + c4];
      acc[0][0] += xa.x * wb.x; acc[0][1] += xa.x * wb.y; acc[0][2] += xa.x * wb.z; acc[0][3] += xa.x * wb.w;
      acc[1][0] += xa.y * wb.x; acc[1][1] += xa.y * wb.y; acc[1][2] += xa.y * wb.z; acc[1][3] += xa.y * wb.w;
      acc[2][0] += xa.z * wb.x; acc[2][1] += xa.z * wb.y; acc[2][2] += xa.z * wb.z; acc[2][3] += xa.z * wb.w;
      acc[3][0] += xa.w * wb.x; acc[3][1] += xa.w * wb.y; acc[3][2] += xa.w * wb.z; acc[3][3] += xa.w * wb.w;
    }
  }
#pragma unroll
  for (int i = 0; i < 4; ++i)
    *(float4*)(Y + (rowbase + r4 + i) * HH + c4) =
        make_float4(acc[i][0], acc[i][1], acc[i][2], acc[i][3]);
}

// ---------------------------------------------------------------------------
// K6: GCN via reverse-CSR gather. 32 lanes per node, each owns 4 channels.
// ---------------------------------------------------------------------------
__global__ __launch_bounds__(256) void k_gcn(const float* __restrict__ y,
                                             const float* __restrict__ dinv,
                                             const int* __restrict__ degi,
                                             const int* __restrict__ cur,
                                             const int2* __restrict__ rev,
                                             const float* __restrict__ bias,
                                             float* __restrict__ hout) {
  const int t = threadIdx.x;
  const int r = blockIdx.x * 8 + (t >> 5);
  const int lane = t & 31;
  const int cnt = degi[r];
  const int off = cur[r] - cnt;
  const float di = dinv[r];

  float4 acc = make_float4(0.f, 0.f, 0.f, 0.f);
  int e = 0;
  for (; e + 2 <= cnt; e += 2) {
    const int2 e0 = rev[off + e];
    const int2 e1 = rev[off + e + 1];
    const float4 y0 = *(const float4*)(y + (size_t)e0.x * HH + lane * 4);
    const float4 y1 = *(const float4*)(y + (size_t)e1.x * HH + lane * 4);
    const float s0 = __int_as_float(e0.y);
    const float s1 = __int_as_float(e1.y);
    acc.x += s0 * y0.x; acc.y += s0 * y0.y; acc.z += s0 * y0.z; acc.w += s0 * y0.w;
    acc.x += s1 * y1.x; acc.y += s1 * y1.y; acc.z += s1 * y1.z; acc.w += s1 * y1.w;
  }
  if (e < cnt) {
    const int2 e0 = rev[off + e];
    const float4 y0 = *(const float4*)(y + (size_t)e0.x * HH + lane * 4);
    const float s0 = __int_as_float(e0.y);
    acc.x += s0 * y0.x; acc.y += s0 * y0.y; acc.z += s0 * y0.z; acc.w += s0 * y0.w;
  }

  const float4 ys = *(const float4*)(y + (size_t)r * HH + lane * 4);
  const float4 bb = *(const float4*)(bias + lane * 4);
  const float t2 = 2.f * di * di;
  float4 h;
  h.x = tanhf(di * acc.x + t2 * ys.x + bb.x);
  h.y = tanhf(di * acc.y + t2 * ys.y + bb.y);
  h.z = tanhf(di * acc.z + t2 * ys.z + bb.z);
  h.w = tanhf(di * acc.w + t2 * ys.w + bb.w);
  *(float4*)(hout + (size_t)r * HH + lane * 4) = h;
}

// ---------------------------------------------------------------------------
// K7: out = (h @ W_out + b_out) * maskf
// ---------------------------------------------------------------------------
__global__ __launch_bounds__(256) void k_out(const float* __restrict__ h,
                                             const float* __restrict__ Wo,
                                             const float* __restrict__ bo,
                                             const float* __restrict__ maskf,
                                             float* __restrict__ out) {
  __shared__ float Ws[HH * OD];
  __shared__ float bs[OD];
  const int t = threadIdx.x;
  for (int q = t; q < HH * OD / 4; q += 256) ((float4*)Ws)[q] = ((const float4*)Wo)[q];
  if (t < OD) bs[t] = bo[t];
  __syncthreads();

  const size_t r = (size_t)blockIdx.x * 256 + t;
  const float4* hrow = (const float4*)(h + r * HH);
  float acc[OD];
#pragma unroll
  for (int o = 0; o < OD; ++o) acc[o] = 0.f;

#pragma unroll 4
  for (int q = 0; q < HH / 4; ++q) {
    const float4 hv = hrow[q];
    const float* w = &Ws[(q * 4) * OD];
#pragma unroll
    for (int o = 0; o < OD; ++o) acc[o] += hv.x * w[o];
#pragma unroll
    for (int o = 0; o < OD; ++o) acc[o] += hv.y * w[OD + o];
#pragma unroll
    for (int o = 0; o < OD; ++o) acc[o] += hv.z * w[2 * OD + o];
#pragma unroll
    for (int o = 0; o < OD; ++o) acc[o] += hv.w * w[3 * OD + o];
  }
  const float mf = maskf[r];
  float4* orow = (float4*)(out + r * OD);
  orow[0] = make_float4((acc[0] + bs[0]) * mf, (acc[1] + bs[1]) * mf,
                        (acc[2] + bs[2]) * mf, (acc[3] + bs[3]) * mf);
  orow[1] = make_float4((acc[4] + bs[4]) * mf, (acc[5] + bs[5]) * mf,
                        (acc[6] + bs[6]) * mf, (acc[7] + bs[7]) * mf);
}

// ---------------------------------------------------------------------------
extern "C" void kernel_launch(void* const* d_in, const int* in_sizes, int n_in,
                              void* d_out, int out_size, void* d_ws, size_t ws_size,
                              hipStream_t stream) {
  (void)in_sizes; (void)n_in; (void)out_size; (void)ws_size;
  const float* obs = (const float*)d_in[0];
  const float* W1  = (const float*)d_in[1];
  const float* b1  = (const float*)d_in[2];
  const float* W2  = (const float*)d_in[3];
  const float* b2  = (const float*)d_in[4];
  const float* Wo  = (const float*)d_in[5];
  const float* bo  = (const float*)d_in[6];
  float* out = (float*)d_out;

  char* ws = (char*)d_ws;
  float* maskf = (float*)(ws);                             // 128 KB
  int*   degi  = (int*)  (ws + (size_t)(128 << 10));       // 128 KB
  float* dinv  = (float*)(ws + (size_t)(256 << 10));       // 128 KB
  float* sbuf  = (float*)(ws + (size_t)(384 << 10));       // 128 KB
  int*   cur   = (int*)  (ws + (size_t)(512 << 10));       // 128 KB
  float2* pxy  = (float2*)(ws + (size_t)(640 << 10));      // 256 KB
  int*   nbr   = (int*)  (ws + (size_t)(1u << 20));        // 2 MB
  int2*  rev   = (int2*) (ws + (size_t)(3u << 20));        // 4 MB
  float* ybuf  = (float*)(ws + (size_t)(7u << 20));        // 16 MB
  float* hbuf  = (float*)(ws + (size_t)(23u << 20));       // 16 MB

  k_mask<<<M_TOT / 256, 256, 0, stream>>>(obs, maskf, degi, pxy);
  k_topk<<<dim3(BB, NN / 32), 256, 0, stream>>>(pxy, maskf, nbr, degi);
  k_dinv<<<M_TOT / 256, 256, 0, stream>>>(degi, maskf, dinv, sbuf);
  k_scan<<<BB, 1024, 0, stream>>>(degi, cur);
  k_fill<<<M_TOT / 256, 256, 0, stream>>>(nbr, maskf, sbuf, cur, rev);

  k_gemm<DD><<<M_TOT / 64, 512, 0, stream>>>(obs, W1, ybuf);
  k_gcn<<<M_TOT / 8, 256, 0, stream>>>(ybuf, dinv, degi, cur, rev, b1, hbuf);
  k_gemm<HH><<<M_TOT / 64, 512, 0, stream>>>(hbuf, W2, ybuf);
  k_gcn<<<M_TOT / 8, 256, 0, stream>>>(ybuf, dinv, degi, cur, rev, b2, hbuf);
  k_out<<<M_TOT / 256, 256, 0, stream>>>(hbuf, Wo, bo, maskf, out);
}

// Round 4
// 190.809 us; speedup vs baseline: 5.3898x; 1.2088x over previous
//
#include <hip/hip_runtime.h>
#include <hip/hip_bf16.h>
#include <math.h>

#define BB 32
#define NN 1024
#define DD 64
#define HH 128
#define KK 16
#define OD 8
#define M_TOT (BB*NN)

typedef unsigned long long u64;

// ---------------------------------------------------------------------------
// K0: mask = any(obs != 0, axis=2); zero degree buffer; emit masked (x,y).
// ---------------------------------------------------------------------------
__global__ __launch_bounds__(256) void k_mask(const float* __restrict__ obs,
                                              float* __restrict__ maskf,
                                              int* __restrict__ degi,
                                              float2* __restrict__ pxy) {
  const int r = blockIdx.x * 256 + threadIdx.x;
  const float4* row = (const float4*)(obs + (size_t)r * DD);
  const float4 v0 = row[0];
  bool any = false;
#pragma unroll
  for (int q = 0; q < DD / 4; ++q) {
    float4 v = row[q];
    any = any || (v.x != 0.f) || (v.y != 0.f) || (v.z != 0.f) || (v.w != 0.f);
  }
  maskf[r] = any ? 1.f : 0.f;
  degi[r] = 0;
  const float inf = __builtin_inff();
  pxy[r] = any ? make_float2(v0.x, v0.y) : make_float2(inf, inf);
}

// bucket = clamp((f32bits >> 21) - 384, 0, 255): exponent + 2 mantissa bits,
// strictly monotone in d2 (d2 >= 0). Covers d2 in [2^-31, 2^33].
static __device__ __forceinline__ int d2bucket(unsigned bits) {
  int v = (int)(bits >> 21) - 384;
  v = v < 0 ? 0 : v;
  return v > 255 ? 255 : v;
}

// ---------------------------------------------------------------------------
// K1: exact 16-NN set per row via histogram selection. 16 lanes/row,
// 16 rows/block. Pass 1: 256-bucket exact count histogram. Scan: find cutoff
// bucket B* (first with cum >= 16) and ndef = cum(<B*) <= 15. Pass 2:
// bucket < B* -> definitely top-16, write nbr + degree; bucket == B* ->
// contender list (exact packed key: d2 bits + index, so JAX's
// lowest-index-on-tie is preserved). Extract the (16-ndef) smallest
// contenders. Downstream math is neighbor-SET-invariant, so nbr order is
// irrelevant. d2 uses explicit IEEE mul/mul/add (no fma) to match ref.
// ---------------------------------------------------------------------------
__global__ __launch_bounds__(256) void k_topk(const float2* __restrict__ pxy,
                                              const float* __restrict__ maskf,
                                              int* __restrict__ nbr,
                                              int* __restrict__ degi) {
  __shared__ float2 pls[NN];            // 8 KB
  __shared__ unsigned hist[16][256];    // 16 KB
  __shared__ u64 lst[16][48];           // 6 KB (cap 48; typical count[B*] ~ 4-8)
  __shared__ int dcnt[16];
  __shared__ int ccnt[16];

  const int b = blockIdx.x;
  const int t = threadIdx.x;
  const int rl = t >> 4;                // row within block, 0..15
  const int s  = t & 15;                // sublane within row, 0..15
  const int row = blockIdx.y * 16 + rl;
  const size_t r = (size_t)b * NN + row;

  for (int q = t; q < NN; q += 256) pls[q] = pxy[b * NN + q];
  for (int q = s; q < 256; q += 16) hist[rl][q] = 0;
  if (s == 0) { dcnt[rl] = 0; ccnt[rl] = 0; }
  __syncthreads();                      // B1: pls + hist-clear visible

  const bool valid = (maskf[r] != 0.f);
  const float2 pi = pls[row];
  const float xi = pi.x, yi = pi.y;

  if (valid) {
#pragma unroll 4
    for (int q = 0; q < NN / 16; ++q) {
      const int j = q * 16 + s;
      const float2 p = pls[j];
      const float dx = __fsub_rn(xi, p.x);
      const float dy = __fsub_rn(yi, p.y);
      const float d2 = __fadd_rn(__fmul_rn(dx, dx), __fmul_rn(dy, dy));
      int bkt = d2bucket(__float_as_uint(d2));
      if (j == row) bkt = 255;          // self: park in top bucket (never reached)
      atomicAdd(&hist[rl][bkt], 1u);
    }
  }
  __syncthreads();                      // B2: histogram complete

  int ndef = 0, need = 0, cem = 0;
  if (valid) {
    // segment sums (16 buckets/lane, uint4 loads) + lane prefix across row
    unsigned seg = 0;
    const uint4* hp = (const uint4*)&hist[rl][s * 16];
#pragma unroll
    for (int i = 0; i < 4; ++i) {
      const uint4 h4 = hp[i];
      seg += h4.x + h4.y + h4.z + h4.w;
    }
    unsigned pre = seg;
#pragma unroll
    for (int off = 1; off < 16; off <<= 1) {
      const unsigned v = __shfl_up(pre, off, 16);
      if (s >= off) pre += v;
    }
    const unsigned preEx = pre - seg;
    int packed = -1;
    if (preEx < 16 && pre >= 16) {      // exactly one lane crosses
      unsigned cum = preEx;
      int Bs = 255, nd = 0;
      for (int i = 0; i < 16; ++i) {
        const unsigned h = hist[rl][s * 16 + i];
        if (cum + h >= 16) { Bs = s * 16 + i; nd = (int)cum; break; }
        cum += h;
      }
      packed = (Bs << 8) | nd;          // nd <= 15 fits low byte
    }
#pragma unroll
    for (int off = 1; off < 16; off <<= 1)
      packed = max(packed, __shfl_xor(packed, off, 16));
    const int Bstar = packed >> 8;
    ndef = packed & 255;
    need = 16 - ndef;

    // pass 2: emit definites directly, contenders to LDS with exact keys
#pragma unroll 4
    for (int q = 0; q < NN / 16; ++q) {
      const int j = q * 16 + s;
      const float2 p = pls[j];
      const float dx = __fsub_rn(xi, p.x);
      const float dy = __fsub_rn(yi, p.y);
      const float d2 = __fadd_rn(__fmul_rn(dx, dx), __fmul_rn(dy, dy));
      int bkt = d2bucket(__float_as_uint(d2));
      if (j == row) bkt = 255;
      if (bkt < Bstar) {
        const int sl = atomicAdd(&dcnt[rl], 1);
        nbr[r * KK + sl] = j;
        atomicAdd(&degi[b * NN + j], 1);
      } else if (bkt == Bstar) {
        const int sl = atomicAdd(&ccnt[rl], 1);
        if (sl < 48) lst[rl][sl] = ((u64)__float_as_uint(d2) << 10) | (unsigned)j;
        ++cem;
      }
    }
  }
  __syncthreads();                      // B3: contender lists visible

  // contender count (register-reduced, no LDS re-read)
  int cn = cem;
#pragma unroll
  for (int off = 1; off < 16; off <<= 1) cn += __shfl_xor(cn, off, 16);
  cn = cn < 48 ? cn : 48;
  if (!valid) { cn = 0; need = 0; }

  u64 k0 = (s      < cn) ? lst[rl][s]      : ~0ull;
  u64 k1 = (s + 16 < cn) ? lst[rl][s + 16] : ~0ull;
  u64 k2 = (s + 32 < cn) ? lst[rl][s + 32] : ~0ull;

  int e = 0;
  while (__any(e < need)) {             // runs max(need) over the wave's rows
    u64 m = k0 < k1 ? k0 : k1;
    m = m < k2 ? m : k2;
#pragma unroll
    for (int off = 1; off < 16; off <<= 1) {
      const u64 o = __shfl_xor(m, off, 16);
      m = o < m ? o : m;
    }
    if (e < need) {
      if (k0 == m) k0 = ~0ull;
      else if (k1 == m) k1 = ~0ull;
      else if (k2 == m) k2 = ~0ull;
      if (s == 0) {
        const int j = (int)(m & (u64)(NN - 1));
        nbr[r * KK + ndef + e] = j;
        atomicAdd(&degi[b * NN + j], 1);
      }
    }
    ++e;
  }
}

// ---------------------------------------------------------------------------
// K2: per-batch exclusive prefix sum of in-degrees -> CSR cursor base;
// fused dinv = deg>0 ? rsqrt(deg) : 0 (deg = count + 2*maskf), s = dinv*maskf.
// ---------------------------------------------------------------------------
__global__ __launch_bounds__(1024) void k_scan(const int* __restrict__ degi,
                                               const float* __restrict__ maskf,
                                               int* __restrict__ cur,
                                               float* __restrict__ dinv,
                                               float* __restrict__ sbuf) {
  __shared__ int wsum[16];
  const int b = blockIdx.x, t = threadIdx.x;
  const int lane = t & 63, w = t >> 6;
  const int d = degi[b * NN + t];
  int x = d;
#pragma unroll
  for (int off = 1; off < 64; off <<= 1) {
    int y = __shfl_up(x, off, 64);
    if (lane >= off) x += y;
  }
  if (lane == 63) wsum[w] = x;

  const float m = maskf[b * NN + t];
  const float deg = (float)d + 2.f * m;
  const float dv = (deg > 0.f) ? (1.f / sqrtf(deg)) : 0.f;
  dinv[b * NN + t] = dv;
  sbuf[b * NN + t] = dv * m;

  __syncthreads();
  if (w == 0) {
    int v = (lane < 16) ? wsum[lane] : 0;
#pragma unroll
    for (int off = 1; off < 16; off <<= 1) {
      int y = __shfl_up(v, off, 64);
      if (lane >= off) v += y;
    }
    if (lane < 16) wsum[lane] = v;
  }
  __syncthreads();
  const int base = b * (NN * KK) + (w ? wsum[w - 1] : 0);
  cur[b * NN + t] = base + x - d;       // exclusive
}

// ---------------------------------------------------------------------------
// K3: fill reverse edge list. rev[pos] = (src_flat, bitcast(s_src)).
// ---------------------------------------------------------------------------
__global__ __launch_bounds__(256) void k_fill(const int* __restrict__ nbr,
                                              const float* __restrict__ maskf,
                                              const float* __restrict__ sbuf,
                                              int* __restrict__ cur,
                                              int2* __restrict__ rev) {
  const int r = blockIdx.x * 256 + threadIdx.x;
  if (maskf[r] == 0.f) return;
  const int bbase = r & ~(NN - 1);
  const float sv = sbuf[r];
  const int4* n4 = (const int4*)(nbr + (size_t)r * KK);
#pragma unroll
  for (int q = 0; q < 4; ++q) {
    int4 v = n4[q];
    int nb[4] = {v.x, v.y, v.z, v.w};
#pragma unroll
    for (int u = 0; u < 4; ++u) {
      const int pos = atomicAdd(&cur[bbase + nb[u]], 1);
      rev[pos] = make_int2(r, __float_as_int(sv));
    }
  }
}

// ---------------------------------------------------------------------------
// K4: Y = X @ W. 64 rows x 128 cols per block, 512 threads, 4x4 acc/thread.
// ---------------------------------------------------------------------------
template <int CIN>
__global__ __launch_bounds__(512) void k_gemm(const float* __restrict__ X,
                                              const float* __restrict__ W,
                                              float* __restrict__ Y) {
  __shared__ float Ws[32 * HH];      // 16 KB
  __shared__ float Xt[32 * 68];      // 8.5 KB, Xt[k][row]
  const int t = threadIdx.x;
  const size_t rowbase = (size_t)blockIdx.x * 64;

  const int c4 = (t & 31) * 4;
  const int r4 = (t >> 5) * 4;

  float acc[4][4] = {{0.f}};

  for (int k0 = 0; k0 < CIN; k0 += 32) {
    __syncthreads();
    {
      const float4* Wt4 = (const float4*)(W + (size_t)k0 * HH);
      ((float4*)Ws)[t]       = Wt4[t];
      ((float4*)Ws)[t + 512] = Wt4[t + 512];
    }
    {
      const int row = t >> 3;        // 0..63
      const int kq  = t & 7;         // 0..7
      float4 v = *(const float4*)(X + (rowbase + row) * CIN + k0 + kq * 4);
      Xt[(kq * 4 + 0) * 68 + row] = v.x;
      Xt[(kq * 4 + 1) * 68 + row] = v.y;
      Xt[(kq * 4 + 2) * 68 + row] = v.z;
      Xt[(kq * 4 + 3) * 68 + row] = v.w;
    }
    __syncthreads();
#pragma unroll
    for (int k = 0; k < 32; ++k) {
      const float4 xa = *(const float4*)&Xt[k * 68 + r4];
      const float4 wb = *(const float4*)&Ws[k * HH + c4];
      acc[0][0] += xa.x * wb.x; acc[0][1] += xa.x * wb.y; acc[0][2] += xa.x * wb.z; acc[0][3] += xa.x * wb.w;
      acc[1][0] += xa.y * wb.x; acc[1][1] += xa.y * wb.y; acc[1][2] += xa.y * wb.z; acc[1][3] += xa.y * wb.w;
      acc[2][0] += xa.z * wb.x; acc[2][1] += xa.z * wb.y; acc[2][2] += xa.z * wb.z; acc[2][3] += xa.z * wb.w;
      acc[3][0] += xa.w * wb.x; acc[3][1] += xa.w * wb.y; acc[3][2] += xa.w * wb.z; acc[3][3] += xa.w * wb.w;
    }
  }
#pragma unroll
  for (int i = 0; i < 4; ++i)
    *(float4*)(Y + (rowbase + r4 + i) * HH + c4) =
        make_float4(acc[i][0], acc[i][1], acc[i][2], acc[i][3]);
}

// ---------------------------------------------------------------------------
// K5: GCN via reverse-CSR gather. 32 lanes per node, each owns 4 channels.
// ---------------------------------------------------------------------------
__global__ __launch_bounds__(256) void k_gcn(const float* __restrict__ y,
                                             const float* __restrict__ dinv,
                                             const int* __restrict__ degi,
                                             const int* __restrict__ cur,
                                             const int2* __restrict__ rev,
                                             const float* __restrict__ bias,
                                             float* __restrict__ hout) {
  const int t = threadIdx.x;
  const int r = blockIdx.x * 8 + (t >> 5);
  const int lane = t & 31;
  const int cnt = degi[r];
  const int off = cur[r] - cnt;
  const float di = dinv[r];

  float4 acc = make_float4(0.f, 0.f, 0.f, 0.f);
  int e = 0;
  for (; e + 2 <= cnt; e += 2) {
    const int2 e0 = rev[off + e];
    const int2 e1 = rev[off + e + 1];
    const float4 y0 = *(const float4*)(y + (size_t)e0.x * HH + lane * 4);
    const float4 y1 = *(const float4*)(y + (size_t)e1.x * HH + lane * 4);
    const float s0 = __int_as_float(e0.y);
    const float s1 = __int_as_float(e1.y);
    acc.x += s0 * y0.x; acc.y += s0 * y0.y; acc.z += s0 * y0.z; acc.w += s0 * y0.w;
    acc.x += s1 * y1.x; acc.y += s1 * y1.y; acc.z += s1 * y1.z; acc.w += s1 * y1.w;
  }
  if (e < cnt) {
    const int2 e0 = rev[off + e];
    const float4 y0 = *(const float4*)(y + (size_t)e0.x * HH + lane * 4);
    const float s0 = __int_as_float(e0.y);
    acc.x += s0 * y0.x; acc.y += s0 * y0.y; acc.z += s0 * y0.z; acc.w += s0 * y0.w;
  }

  const float4 ys = *(const float4*)(y + (size_t)r * HH + lane * 4);
  const float4 bb = *(const float4*)(bias + lane * 4);
  const float t2 = 2.f * di * di;
  float4 h;
  h.x = tanhf(di * acc.x + t2 * ys.x + bb.x);
  h.y = tanhf(di * acc.y + t2 * ys.y + bb.y);
  h.z = tanhf(di * acc.z + t2 * ys.z + bb.z);
  h.w = tanhf(di * acc.w + t2 * ys.w + bb.w);
  *(float4*)(hout + (size_t)r * HH + lane * 4) = h;
}

// ---------------------------------------------------------------------------
// K6: out = (h @ W_out + b_out) * maskf
// ---------------------------------------------------------------------------
__global__ __launch_bounds__(256) void k_out(const float* __restrict__ h,
                                             const float* __restrict__ Wo,
                                             const float* __restrict__ bo,
                                             const float* __restrict__ maskf,
                                             float* __restrict__ out) {
  __shared__ float Ws[HH * OD];
  __shared__ float bs[OD];
  const int t = threadIdx.x;
  for (int q = t; q < HH * OD / 4; q += 256) ((float4*)Ws)[q] = ((const float4*)Wo)[q];
  if (t < OD) bs[t] = bo[t];
  __syncthreads();

  const size_t r = (size_t)blockIdx.x * 256 + t;
  const float4* hrow = (const float4*)(h + r * HH);
  float acc[OD];
#pragma unroll
  for (int o = 0; o < OD; ++o) acc[o] = 0.f;

#pragma unroll 4
  for (int q = 0; q < HH / 4; ++q) {
    const float4 hv = hrow[q];
    const float* w = &Ws[(q * 4) * OD];
#pragma unroll
    for (int o = 0; o < OD; ++o) acc[o] += hv.x * w[o];
#pragma unroll
    for (int o = 0; o < OD; ++o) acc[o] += hv.y * w[OD + o];
#pragma unroll
    for (int o = 0; o < OD; ++o) acc[o] += hv.z * w[2 * OD + o];
#pragma unroll
    for (int o = 0; o < OD; ++o) acc[o] += hv.w * w[3 * OD + o];
  }
  const float mf = maskf[r];
  float4* orow = (float4*)(out + r * OD);
  orow[0] = make_float4((acc[0] + bs[0]) * mf, (acc[1] + bs[1]) * mf,
                        (acc[2] + bs[2]) * mf, (acc[3] + bs[3]) * mf);
  orow[1] = make_float4((acc[4] + bs[4]) * mf, (acc[5] + bs[5]) * mf,
                        (acc[6] + bs[6]) * mf, (acc[7] + bs[7]) * mf);
}

// ---------------------------------------------------------------------------
extern "C" void kernel_launch(void* const* d_in, const int* in_sizes, int n_in,
                              void* d_out, int out_size, void* d_ws, size_t ws_size,
                              hipStream_t stream) {
  (void)in_sizes; (void)n_in; (void)out_size; (void)ws_size;
  const float* obs = (const float*)d_in[0];
  const float* W1  = (const float*)d_in[1];
  const float* b1  = (const float*)d_in[2];
  const float* W2  = (const float*)d_in[3];
  const float* b2  = (const float*)d_in[4];
  const float* Wo  = (const float*)d_in[5];
  const float* bo  = (const float*)d_in[6];
  float* out = (float*)d_out;

  char* ws = (char*)d_ws;
  float* maskf = (float*)(ws);                             // 128 KB
  int*   degi  = (int*)  (ws + (size_t)(128 << 10));       // 128 KB
  float* dinv  = (float*)(ws + (size_t)(256 << 10));       // 128 KB
  float* sbuf  = (float*)(ws + (size_t)(384 << 10));       // 128 KB
  int*   cur   = (int*)  (ws + (size_t)(512 << 10));       // 128 KB
  float2* pxy  = (float2*)(ws + (size_t)(640 << 10));      // 256 KB
  int*   nbr   = (int*)  (ws + (size_t)(1u << 20));        // 2 MB
  int2*  rev   = (int2*) (ws + (size_t)(3u << 20));        // 4 MB
  float* ybuf  = (float*)(ws + (size_t)(7u << 20));        // 16 MB
  float* hbuf  = (float*)(ws + (size_t)(23u << 20));       // 16 MB

  k_mask<<<M_TOT / 256, 256, 0, stream>>>(obs, maskf, degi, pxy);
  k_topk<<<dim3(BB, NN / 16), 256, 0, stream>>>(pxy, maskf, nbr, degi);
  k_scan<<<BB, 1024, 0, stream>>>(degi, maskf, cur, dinv, sbuf);
  k_fill<<<M_TOT / 256, 256, 0, stream>>>(nbr, maskf, sbuf, cur, rev);

  k_gemm<DD><<<M_TOT / 64, 512, 0, stream>>>(obs, W1, ybuf);
  k_gcn<<<M_TOT / 8, 256, 0, stream>>>(ybuf, dinv, degi, cur, rev, b1, hbuf);
  k_gemm<HH><<<M_TOT / 64, 512, 0, stream>>>(hbuf, W2, ybuf);
  k_gcn<<<M_TOT / 8, 256, 0, stream>>>(ybuf, dinv, degi, cur, rev, b2, hbuf);
  k_out<<<M_TOT / 256, 256, 0, stream>>>(hbuf, Wo, bo, maskf, out);
}

// Round 5
// 169.756 us; speedup vs baseline: 6.0583x; 1.1240x over previous
//
#include <hip/hip_runtime.h>
#include <hip/hip_bf16.h>
#include <math.h>

#define BB 32
#define NN 1024
#define DD 64
#define HH 128
#define KK 16
#define OD 8
#define M_TOT (BB*NN)

typedef unsigned long long u64;

// bucket = clamp((f32bits >> 21) - 384, 0, 255): exponent + 2 mantissa bits,
// strictly monotone in d2 (d2 >= 0).
static __device__ __forceinline__ int d2bucket(unsigned bits) {
  int v = (int)(bits >> 21) - 384;
  v = v < 0 ? 0 : v;
  return v > 255 ? 255 : v;
}

// ---------------------------------------------------------------------------
// K1: Y = X @ W (64 rows x 128 cols / block, 512 thr, 4x4 acc/thread).
// EMIT_MASK: during X staging also compute mask = any(row != 0), emit
// maskf / pxy (inf-masked x,y) / degi = 0 — replaces the old k_mask kernel.
// ---------------------------------------------------------------------------
template <int CIN, bool EMIT_MASK>
__global__ __launch_bounds__(512) void k_gemm(const float* __restrict__ X,
                                              const float* __restrict__ W,
                                              float* __restrict__ Y,
                                              float* __restrict__ maskf,
                                              int* __restrict__ degi,
                                              float2* __restrict__ pxy) {
  __shared__ float Ws[32 * HH];      // 16 KB
  __shared__ float Xt[32 * 68];      // 8.5 KB, Xt[k][row]
  __shared__ int rowflag[64];
  __shared__ float2 praw[64];
  const int t = threadIdx.x;
  const size_t rowbase = (size_t)blockIdx.x * 64;

  if (EMIT_MASK && t < 64) rowflag[t] = 0;

  const int c4 = (t & 31) * 4;
  const int r4 = (t >> 5) * 4;

  float acc[4][4] = {{0.f}};

  for (int k0 = 0; k0 < CIN; k0 += 32) {
    __syncthreads();
    {
      const float4* Wt4 = (const float4*)(W + (size_t)k0 * HH);
      ((float4*)Ws)[t]       = Wt4[t];
      ((float4*)Ws)[t + 512] = Wt4[t + 512];
    }
    {
      const int row = t >> 3;        // 0..63
      const int kq  = t & 7;         // 0..7
      float4 v = *(const float4*)(X + (rowbase + row) * CIN + k0 + kq * 4);
      if (EMIT_MASK) {
        if (v.x != 0.f || v.y != 0.f || v.z != 0.f || v.w != 0.f)
          rowflag[row] = 1;          // benign race: all writers store 1
        if (k0 == 0 && kq == 0) praw[row] = make_float2(v.x, v.y);
      }
      Xt[(kq * 4 + 0) * 68 + row] = v.x;
      Xt[(kq * 4 + 1) * 68 + row] = v.y;
      Xt[(kq * 4 + 2) * 68 + row] = v.z;
      Xt[(kq * 4 + 3) * 68 + row] = v.w;
    }
    __syncthreads();
#pragma unroll
    for (int k = 0; k < 32; ++k) {
      const float4 xa = *(const float4*)&Xt[k * 68 + r4];
      const float4 wb = *(const float4*)&Ws[k * HH + c4];
      acc[0][0] += xa.x * wb.x; acc[0][1] += xa.x * wb.y; acc[0][2] += xa.x * wb.z; acc[0][3] += xa.x * wb.w;
      acc[1][0] += xa.y * wb.x; acc[1][1] += xa.y * wb.y; acc[1][2] += xa.y * wb.z; acc[1][3] += xa.y * wb.w;
      acc[2][0] += xa.z * wb.x; acc[2][1] += xa.z * wb.y; acc[2][2] += xa.z * wb.z; acc[2][3] += xa.z * wb.w;
      acc[3][0] += xa.w * wb.x; acc[3][1] += xa.w * wb.y; acc[3][2] += xa.w * wb.z; acc[3][3] += xa.w * wb.w;
    }
  }
#pragma unroll
  for (int i = 0; i < 4; ++i)
    *(float4*)(Y + (rowbase + r4 + i) * HH + c4) =
        make_float4(acc[i][0], acc[i][1], acc[i][2], acc[i][3]);

  if (EMIT_MASK && t < 64) {
    // rowflag/praw writes all precede the last inner __syncthreads -> visible
    const size_t gr = rowbase + t;
    const int any = rowflag[t];
    maskf[gr] = any ? 1.f : 0.f;
    degi[gr] = 0;
    const float inf = __builtin_inff();
    pxy[gr] = any ? praw[t] : make_float2(inf, inf);
  }
}

// ---------------------------------------------------------------------------
// K2: exact 16-NN set per row via histogram selection (see R4 notes).
// ---------------------------------------------------------------------------
__global__ __launch_bounds__(256) void k_topk(const float2* __restrict__ pxy,
                                              const float* __restrict__ maskf,
                                              int* __restrict__ nbr,
                                              int* __restrict__ degi) {
  __shared__ float2 pls[NN];            // 8 KB
  __shared__ unsigned hist[16][256];    // 16 KB
  __shared__ u64 lst[16][48];           // 6 KB
  __shared__ int dcnt[16];
  __shared__ int ccnt[16];

  const int b = blockIdx.x;
  const int t = threadIdx.x;
  const int rl = t >> 4;                // row within block, 0..15
  const int s  = t & 15;                // sublane within row, 0..15
  const int row = blockIdx.y * 16 + rl;
  const size_t r = (size_t)b * NN + row;

  for (int q = t; q < NN; q += 256) pls[q] = pxy[b * NN + q];
  for (int q = s; q < 256; q += 16) hist[rl][q] = 0;
  if (s == 0) { dcnt[rl] = 0; ccnt[rl] = 0; }
  __syncthreads();

  const bool valid = (maskf[r] != 0.f);
  const float2 pi = pls[row];
  const float xi = pi.x, yi = pi.y;

  if (valid) {
#pragma unroll 4
    for (int q = 0; q < NN / 16; ++q) {
      const int j = q * 16 + s;
      const float2 p = pls[j];
      const float dx = __fsub_rn(xi, p.x);
      const float dy = __fsub_rn(yi, p.y);
      const float d2 = __fadd_rn(__fmul_rn(dx, dx), __fmul_rn(dy, dy));
      int bkt = d2bucket(__float_as_uint(d2));
      if (j == row) bkt = 255;
      atomicAdd(&hist[rl][bkt], 1u);
    }
  }
  __syncthreads();

  int ndef = 0, need = 0, cem = 0;
  if (valid) {
    unsigned seg = 0;
    const uint4* hp = (const uint4*)&hist[rl][s * 16];
#pragma unroll
    for (int i = 0; i < 4; ++i) {
      const uint4 h4 = hp[i];
      seg += h4.x + h4.y + h4.z + h4.w;
    }
    unsigned pre = seg;
#pragma unroll
    for (int off = 1; off < 16; off <<= 1) {
      const unsigned v = __shfl_up(pre, off, 16);
      if (s >= off) pre += v;
    }
    const unsigned preEx = pre - seg;
    int packed = -1;
    if (preEx < 16 && pre >= 16) {
      unsigned cum = preEx;
      int Bs = 255, nd = 0;
      for (int i = 0; i < 16; ++i) {
        const unsigned h = hist[rl][s * 16 + i];
        if (cum + h >= 16) { Bs = s * 16 + i; nd = (int)cum; break; }
        cum += h;
      }
      packed = (Bs << 8) | nd;
    }
#pragma unroll
    for (int off = 1; off < 16; off <<= 1)
      packed = max(packed, __shfl_xor(packed, off, 16));
    const int Bstar = packed >> 8;
    ndef = packed & 255;
    need = 16 - ndef;

#pragma unroll 4
    for (int q = 0; q < NN / 16; ++q) {
      const int j = q * 16 + s;
      const float2 p = pls[j];
      const float dx = __fsub_rn(xi, p.x);
      const float dy = __fsub_rn(yi, p.y);
      const float d2 = __fadd_rn(__fmul_rn(dx, dx), __fmul_rn(dy, dy));
      int bkt = d2bucket(__float_as_uint(d2));
      if (j == row) bkt = 255;
      if (bkt < Bstar) {
        const int sl = atomicAdd(&dcnt[rl], 1);
        nbr[r * KK + sl] = j;
        atomicAdd(&degi[b * NN + j], 1);
      } else if (bkt == Bstar) {
        const int sl = atomicAdd(&ccnt[rl], 1);
        if (sl < 48) lst[rl][sl] = ((u64)__float_as_uint(d2) << 10) | (unsigned)j;
        ++cem;
      }
    }
  }
  __syncthreads();

  int cn = cem;
#pragma unroll
  for (int off = 1; off < 16; off <<= 1) cn += __shfl_xor(cn, off, 16);
  cn = cn < 48 ? cn : 48;
  if (!valid) { cn = 0; need = 0; }

  u64 k0 = (s      < cn) ? lst[rl][s]      : ~0ull;
  u64 k1 = (s + 16 < cn) ? lst[rl][s + 16] : ~0ull;
  u64 k2 = (s + 32 < cn) ? lst[rl][s + 32] : ~0ull;

  int e = 0;
  while (__any(e < need)) {
    u64 m = k0 < k1 ? k0 : k1;
    m = m < k2 ? m : k2;
#pragma unroll
    for (int off = 1; off < 16; off <<= 1) {
      const u64 o = __shfl_xor(m, off, 16);
      m = o < m ? o : m;
    }
    if (e < need) {
      if (k0 == m) k0 = ~0ull;
      else if (k1 == m) k1 = ~0ull;
      else if (k2 == m) k2 = ~0ull;
      if (s == 0) {
        const int j = (int)(m & (u64)(NN - 1));
        nbr[r * KK + ndef + e] = j;
        atomicAdd(&degi[b * NN + j], 1);
      }
    }
    ++e;
  }
}

// ---------------------------------------------------------------------------
// K3: per-batch scan + dinv + reverse-edge fill (LDS cursors), one block
// per batch. cur[r] = global START of r's segment; rev[pos]=(src, s_src).
// ---------------------------------------------------------------------------
__global__ __launch_bounds__(1024) void k_graph(const int* __restrict__ degi,
                                                const float* __restrict__ maskf,
                                                const int* __restrict__ nbr,
                                                int* __restrict__ cur,
                                                float* __restrict__ dinv,
                                                int2* __restrict__ rev) {
  __shared__ int wsum[16];
  __shared__ int lcur[NN];
  const int b = blockIdx.x, t = threadIdx.x;
  const int lane = t & 63, w = t >> 6;
  const int r = b * NN + t;
  const int d = degi[r];
  int x = d;
#pragma unroll
  for (int off = 1; off < 64; off <<= 1) {
    int y = __shfl_up(x, off, 64);
    if (lane >= off) x += y;
  }
  if (lane == 63) wsum[w] = x;

  const float m = maskf[r];
  const float deg = (float)d + 2.f * m;
  const float dv = (deg > 0.f) ? (1.f / sqrtf(deg)) : 0.f;
  dinv[r] = dv;
  const float sv = dv * m;

  __syncthreads();
  if (w == 0) {
    int v = (lane < 16) ? wsum[lane] : 0;
#pragma unroll
    for (int off = 1; off < 16; off <<= 1) {
      int y = __shfl_up(v, off, 64);
      if (lane >= off) v += y;
    }
    if (lane < 16) wsum[lane] = v;
  }
  __syncthreads();
  const int start = b * (NN * KK) + (w ? wsum[w - 1] : 0) + x - d;  // exclusive
  lcur[t] = start;
  cur[r] = start;
  __syncthreads();

  if (m != 0.f) {
    const int sb = __float_as_int(sv);
    const int4* n4 = (const int4*)(nbr + (size_t)r * KK);
#pragma unroll
    for (int q = 0; q < 4; ++q) {
      int4 v = n4[q];
      int nb[4] = {v.x, v.y, v.z, v.w};
#pragma unroll
      for (int u = 0; u < 4; ++u) {
        const int pos = atomicAdd(&lcur[nb[u]], 1);
        rev[pos] = make_int2(r, sb);
      }
    }
  }
}

// ---------------------------------------------------------------------------
// K4: GCN via reverse-CSR gather. 32 lanes per node, each owns 4 channels.
// FUSE_OUT: instead of storing h, fold in the output projection:
// out = (h @ W_out + b_out) * maskf, reduced across the 32-lane group.
// ---------------------------------------------------------------------------
template <bool FUSE_OUT>
__global__ __launch_bounds__(256) void k_gcn(const float* __restrict__ y,
                                             const float* __restrict__ dinv,
                                             const int* __restrict__ degi,
                                             const int* __restrict__ cur,
                                             const int2* __restrict__ rev,
                                             const float* __restrict__ bias,
                                             float* __restrict__ hout,
                                             const float* __restrict__ Wo,
                                             const float* __restrict__ bo,
                                             const float* __restrict__ maskf,
                                             float* __restrict__ out) {
  const int t = threadIdx.x;
  const int r = blockIdx.x * 8 + (t >> 5);
  const int lane = t & 31;
  const int cnt = degi[r];
  const int off = cur[r];
  const float di = dinv[r];

  float4 acc = make_float4(0.f, 0.f, 0.f, 0.f);
  int e = 0;
  for (; e + 2 <= cnt; e += 2) {
    const int2 e0 = rev[off + e];
    const int2 e1 = rev[off + e + 1];
    const float4 y0 = *(const float4*)(y + (size_t)e0.x * HH + lane * 4);
    const float4 y1 = *(const float4*)(y + (size_t)e1.x * HH + lane * 4);
    const float s0 = __int_as_float(e0.y);
    const float s1 = __int_as_float(e1.y);
    acc.x += s0 * y0.x; acc.y += s0 * y0.y; acc.z += s0 * y0.z; acc.w += s0 * y0.w;
    acc.x += s1 * y1.x; acc.y += s1 * y1.y; acc.z += s1 * y1.z; acc.w += s1 * y1.w;
  }
  if (e < cnt) {
    const int2 e0 = rev[off + e];
    const float4 y0 = *(const float4*)(y + (size_t)e0.x * HH + lane * 4);
    const float s0 = __int_as_float(e0.y);
    acc.x += s0 * y0.x; acc.y += s0 * y0.y; acc.z += s0 * y0.z; acc.w += s0 * y0.w;
  }

  const float4 ys = *(const float4*)(y + (size_t)r * HH + lane * 4);
  const float4 bb = *(const float4*)(bias + lane * 4);
  const float t2 = 2.f * di * di;
  float4 h;
  h.x = tanhf(di * acc.x + t2 * ys.x + bb.x);
  h.y = tanhf(di * acc.y + t2 * ys.y + bb.y);
  h.z = tanhf(di * acc.z + t2 * ys.z + bb.z);
  h.w = tanhf(di * acc.w + t2 * ys.w + bb.w);

  if (!FUSE_OUT) {
    *(float4*)(hout + (size_t)r * HH + lane * 4) = h;
  } else {
    // lane holds channels c0..c0+3, c0 = lane*4; Wo rows in registers (4KB total, cached)
    const float4* W4 = (const float4*)(Wo + (size_t)lane * 4 * OD);
    float o8[OD];
#pragma unroll
    for (int o = 0; o < OD; ++o) o8[o] = 0.f;
#pragma unroll
    for (int cc = 0; cc < 4; ++cc) {
      const float hc = (cc == 0) ? h.x : (cc == 1) ? h.y : (cc == 2) ? h.z : h.w;
      const float4 wa = W4[cc * 2];
      const float4 wbq = W4[cc * 2 + 1];
      o8[0] += hc * wa.x;  o8[1] += hc * wa.y;  o8[2] += hc * wa.z;  o8[3] += hc * wa.w;
      o8[4] += hc * wbq.x; o8[5] += hc * wbq.y; o8[6] += hc * wbq.z; o8[7] += hc * wbq.w;
    }
#pragma unroll
    for (int offx = 1; offx < 32; offx <<= 1) {
#pragma unroll
      for (int o = 0; o < OD; ++o) o8[o] += __shfl_xor(o8[o], offx, 32);
    }
    if (lane == 0) {
      const float mf = maskf[r];
      const float4 b0 = *(const float4*)(bo);
      const float4 b1 = *(const float4*)(bo + 4);
      float4* orow = (float4*)(out + (size_t)r * OD);
      orow[0] = make_float4((o8[0] + b0.x) * mf, (o8[1] + b0.y) * mf,
                            (o8[2] + b0.z) * mf, (o8[3] + b0.w) * mf);
      orow[1] = make_float4((o8[4] + b1.x) * mf, (o8[5] + b1.y) * mf,
                            (o8[6] + b1.z) * mf, (o8[7] + b1.w) * mf);
    }
  }
}

// ---------------------------------------------------------------------------
extern "C" void kernel_launch(void* const* d_in, const int* in_sizes, int n_in,
                              void* d_out, int out_size, void* d_ws, size_t ws_size,
                              hipStream_t stream) {
  (void)in_sizes; (void)n_in; (void)out_size; (void)ws_size;
  const float* obs = (const float*)d_in[0];
  const float* W1  = (const float*)d_in[1];
  const float* b1  = (const float*)d_in[2];
  const float* W2  = (const float*)d_in[3];
  const float* b2  = (const float*)d_in[4];
  const float* Wo  = (const float*)d_in[5];
  const float* bo  = (const float*)d_in[6];
  float* out = (float*)d_out;

  char* ws = (char*)d_ws;
  float* maskf = (float*)(ws);                             // 128 KB
  int*   degi  = (int*)  (ws + (size_t)(128 << 10));       // 128 KB
  float* dinv  = (float*)(ws + (size_t)(256 << 10));       // 128 KB
  int*   cur   = (int*)  (ws + (size_t)(384 << 10));       // 128 KB
  float2* pxy  = (float2*)(ws + (size_t)(512 << 10));      // 256 KB
  int*   nbr   = (int*)  (ws + (size_t)(1u << 20));        // 2 MB
  int2*  rev   = (int2*) (ws + (size_t)(3u << 20));        // 4 MB
  float* ybuf  = (float*)(ws + (size_t)(7u << 20));        // 16 MB
  float* hbuf  = (float*)(ws + (size_t)(23u << 20));       // 16 MB

  k_gemm<DD, true><<<M_TOT / 64, 512, 0, stream>>>(obs, W1, ybuf, maskf, degi, pxy);
  k_topk<<<dim3(BB, NN / 16), 256, 0, stream>>>(pxy, maskf, nbr, degi);
  k_graph<<<BB, 1024, 0, stream>>>(degi, maskf, nbr, cur, dinv, rev);
  k_gcn<false><<<M_TOT / 8, 256, 0, stream>>>(ybuf, dinv, degi, cur, rev, b1, hbuf,
                                              nullptr, nullptr, nullptr, nullptr);
  k_gemm<HH, false><<<M_TOT / 64, 512, 0, stream>>>(hbuf, W2, ybuf, nullptr, nullptr, nullptr);
  k_gcn<true><<<M_TOT / 8, 256, 0, stream>>>(ybuf, dinv, degi, cur, rev, b2, nullptr,
                                             Wo, bo, maskf, out);
}